// Round 10
// baseline (91.514 us; speedup 1.0000x reference)
//
#include <hip/hip_runtime.h>
#include <hip/hip_bf16.h>

// Bilinear CNN pooling: dotted[b,c,d] = sum_x L[b,x,c]*R[b,x,d]  (B=32, X=12544, C=128)
// then signed-sqrt + global L2-normalize per batch.
//
// Round 10: r6 structure (best: 87.8us) with register lookahead extended 3->4
// (tile s -> parity s%4; WRITE consumes loads issued 3 iters back). 4-unrolled
// branch-free main loop. Everything else identical to r6.

#define NK      8             // K-chunks per batch
#define KC      1568          // 12544 / 8
#define BK      32            // K per tile
#define NT      49            // KC / BK
#define BATCH   32
#define CDIM    128
#define XDIM    12544

typedef __bf16 bf16x8 __attribute__((ext_vector_type(8)));
typedef float  f32x16 __attribute__((ext_vector_type(16)));

// 16 MB partial buffer + per-segment sumsq; fully rewritten before read each launch.
__device__ float g_part[(size_t)NK * BATCH * CDIM * CDIM];
__device__ float g_ssq[BATCH * 16];

// Split 8 f32 -> RNE-bf16 hi + trunc-bf16 lo, packed into uint4s (validated r1-r9).
__device__ __forceinline__ void split8(const float* f, uint4& hi, uint4& lo) {
  uint xh[8], xl[8];
#pragma unroll
  for (int i = 0; i < 8; ++i) {
    uint u = __float_as_uint(f[i]);
    uint r = u + 0x7FFFu + ((u >> 16) & 1u);        // RNE bf16 in top 16 bits
    xh[i] = r;
    float hif = __uint_as_float(r & 0xFFFF0000u);    // exact hi value
    xl[i] = __float_as_uint(f[i] - hif);             // exact residual, trunc on pack
  }
  hi.x = __builtin_amdgcn_perm(xh[1], xh[0], 0x07060302u);
  hi.y = __builtin_amdgcn_perm(xh[3], xh[2], 0x07060302u);
  hi.z = __builtin_amdgcn_perm(xh[5], xh[4], 0x07060302u);
  hi.w = __builtin_amdgcn_perm(xh[7], xh[6], 0x07060302u);
  lo.x = __builtin_amdgcn_perm(xl[1], xl[0], 0x07060302u);
  lo.y = __builtin_amdgcn_perm(xl[3], xl[2], 0x07060302u);
  lo.z = __builtin_amdgcn_perm(xl[5], xl[4], 0x07060302u);
  lo.w = __builtin_amdgcn_perm(xl[7], xl[6], 0x07060302u);
}

// LDS 16B-unit index for (column c, k-half kh) within one 16-k substep (r4-r9 validated).
__device__ __forceinline__ int ldsu(int c, int kh) {
  return ((c << 1) | kh) ^ ((c >> 2) & 7);
}

// ---------------------------------------------------------------------------
// Kernel 1: per (chunk, batch): partial[c][d] = sum_{k in chunk} L[k][c]*R[k][d]
// 512 threads = 8 waves (2x4 grid of 64x32 tiles, 32x32x16 MFMA, 3-pass split).
// LDS: [set][substep][unit]; 64 KB. Tile = 32 k-rows, two 16-k substeps.
// ---------------------------------------------------------------------------
__global__ __launch_bounds__(512, 2)
void bcnn_gemm_kernel(const float* __restrict__ L, const float* __restrict__ R) {
  __shared__ uint4 sAhi[2][2][256], sAlo[2][2][256];
  __shared__ uint4 sBhi[2][2][256], sBlo[2][2][256];

  const int chunk = blockIdx.x;      // 0..7
  const int b     = blockIdx.y;
  const int t     = threadIdx.x;
  const int l     = t & 63;
  const int w     = t >> 6;
  const int wr    = w >> 2;          // 0..1
  const int wc    = w & 3;           // 0..3
  const int lc    = l & 31;
  const int hh    = l >> 5;          // k-half selector within a substep

  // staging: thread owns column sc, k-rows sh*8 .. sh*8+7 of each 32-k tile
  const int sc  = t & 127;
  const int sh  = t >> 7;            // 0..3
  const int sub = sh >> 1;           // substep region 0/1
  const int wu  = ldsu(sc, sh & 1);

  const float* gL = L + ((size_t)b * XDIM + (size_t)chunk * KC + sh * 8) * CDIM + sc;
  const float* gR = R + ((size_t)b * XDIM + (size_t)chunk * KC + sh * 8) * CDIM + sc;

  // fragment units (per substep)
  const int cA0 = wr * 64 + lc;
  const int cA1 = cA0 + 32;
  const int dB  = wc * 32 + lc;
  const int uA0 = ldsu(cA0, hh);
  const int uA1 = ldsu(cA1, hh);
  const int uB  = ldsu(dB,  hh);

  f32x16 acc0 = {};
  f32x16 acc1 = {};

  // four static register-parity sets (tile s has parity s % 4)
  float rlA[8], rrA[8], rlB[8], rrB[8], rlC[8], rrC[8], rlD[8], rrD[8];

#define LOADR(rl, rr, s)                                                        \
  do {                                                                          \
    const float* pL_ = gL + (size_t)(s) * BK * CDIM;                            \
    const float* pR_ = gR + (size_t)(s) * BK * CDIM;                            \
    _Pragma("unroll")                                                           \
    for (int i = 0; i < 8; ++i) { rl[i] = pL_[i * CDIM]; rr[i] = pR_[i * CDIM]; } \
  } while (0)

#define WRITE(rl, rr, set)                                                      \
  do {                                                                          \
    uint4 hi_, lo_;                                                             \
    split8(rl, hi_, lo_);                                                       \
    sAhi[set][sub][wu] = hi_; sAlo[set][sub][wu] = lo_;                         \
    split8(rr, hi_, lo_);                                                       \
    sBhi[set][sub][wu] = hi_; sBlo[set][sub][wu] = lo_;                         \
  } while (0)

#define COMPUTE(set)                                                            \
  do {                                                                          \
    _Pragma("unroll")                                                           \
    for (int ss = 0; ss < 2; ++ss) {                                            \
      bf16x8 ah0 = *(const bf16x8*)&sAhi[set][ss][uA0];                         \
      bf16x8 al0 = *(const bf16x8*)&sAlo[set][ss][uA0];                         \
      bf16x8 ah1 = *(const bf16x8*)&sAhi[set][ss][uA1];                         \
      bf16x8 al1 = *(const bf16x8*)&sAlo[set][ss][uA1];                         \
      bf16x8 bh  = *(const bf16x8*)&sBhi[set][ss][uB];                          \
      bf16x8 bl  = *(const bf16x8*)&sBlo[set][ss][uB];                          \
      acc0 = __builtin_amdgcn_mfma_f32_32x32x16_bf16(ah0, bh, acc0, 0, 0, 0);   \
      acc1 = __builtin_amdgcn_mfma_f32_32x32x16_bf16(ah1, bh, acc1, 0, 0, 0);   \
      acc0 = __builtin_amdgcn_mfma_f32_32x32x16_bf16(ah0, bl, acc0, 0, 0, 0);   \
      acc1 = __builtin_amdgcn_mfma_f32_32x32x16_bf16(ah1, bl, acc1, 0, 0, 0);   \
      acc0 = __builtin_amdgcn_mfma_f32_32x32x16_bf16(al0, bh, acc0, 0, 0, 0);   \
      acc1 = __builtin_amdgcn_mfma_f32_32x32x16_bf16(al1, bh, acc1, 0, 0, 0);   \
    }                                                                           \
  } while (0)

#define BAR()                                                                   \
  do {                                                                          \
    asm volatile("s_waitcnt lgkmcnt(0)" ::: "memory");                          \
    __builtin_amdgcn_s_barrier();                                               \
  } while (0)

  // prologue: tiles 0..3 in flight (4-deep); write tile 0
  LOADR(rlA, rrA, 0);
  LOADR(rlB, rrB, 1);
  LOADR(rlC, rrC, 2);
  LOADR(rlD, rrD, 3);
  WRITE(rlA, rrA, 0);
  BAR();

  // steady state: iter s -> LOAD tile s+4 into parity s%4; COMPUTE set s&1;
  // WRITE tile s+1 (loaded at iter s-3) into set (s+1)&1. 4-unrolled.
  for (int it = 0; it < 11; ++it) {
    const int s0 = 4 * it;
    /* s0+0 */ LOADR(rlA, rrA, s0 + 4); COMPUTE(0); WRITE(rlB, rrB, 1); BAR();
    /* s0+1 */ LOADR(rlB, rrB, s0 + 5); COMPUTE(1); WRITE(rlC, rrC, 0); BAR();
    /* s0+2 */ LOADR(rlC, rrC, s0 + 6); COMPUTE(0); WRITE(rlD, rrD, 1); BAR();
    /* s0+3 */ LOADR(rlD, rrD, s0 + 7); COMPUTE(1); WRITE(rlA, rrA, 0); BAR();
  }
  // peeled tail: s = 44..48 (last load is tile 48 at s=44)
  /* s=44 */ LOADR(rlA, rrA, 48); COMPUTE(0); WRITE(rlB, rrB, 1); BAR();
  /* s=45 */ COMPUTE(1); WRITE(rlC, rrC, 0); BAR();
  /* s=46 */ COMPUTE(0); WRITE(rlD, rrD, 1); BAR();
  /* s=47 */ COMPUTE(1); WRITE(rlA, rrA, 0); BAR();
  /* s=48 */ COMPUTE(0);

#undef LOADR
#undef WRITE
#undef COMPUTE
#undef BAR

  // C/D layout (HW-validated r1-r9): col = lane&31, row = (r&3)+8*(r>>2)+4*hh
  float* outp = g_part + (((size_t)chunk * BATCH + b) << 14);
#pragma unroll
  for (int r = 0; r < 16; ++r) {
    const int row = (r & 3) + ((r >> 2) << 3) + (hh << 2);
    outp[(size_t)(wr * 64 + row) * CDIM + (wc * 32 + lc)]      = acc0[r];
    outp[(size_t)(wr * 64 + 32 + row) * CDIM + (wc * 32 + lc)] = acc1[r];
  }
}

// ---------------------------------------------------------------------------
// Kernel 2a: sum NK partials, signed-sqrt, write sqrted, per-segment sumsq.
// ---------------------------------------------------------------------------
__global__ void bcnn_sqrt_kernel(float* __restrict__ out) {
  const int b   = blockIdx.y;
  const int seg = blockIdx.x;
  const int t   = threadIdx.x;
  const int idx = seg * 1024 + t * 4;

  float4 v = {0.f, 0.f, 0.f, 0.f};
#pragma unroll
  for (int ch = 0; ch < NK; ++ch) {
    const float4 p = *(const float4*)&g_part[(((size_t)ch * BATCH + b) << 14) + idx];
    v.x += p.x; v.y += p.y; v.z += p.z; v.w += p.w;
  }
  float4 sv;
  {
    float a;
    a = sqrtf(fabsf(v.x) + 1e-9f); sv.x = (v.x > 0.f) ? a : ((v.x < 0.f) ? -a : 0.f);
    a = sqrtf(fabsf(v.y) + 1e-9f); sv.y = (v.y > 0.f) ? a : ((v.y < 0.f) ? -a : 0.f);
    a = sqrtf(fabsf(v.z) + 1e-9f); sv.z = (v.z > 0.f) ? a : ((v.z < 0.f) ? -a : 0.f);
    a = sqrtf(fabsf(v.w) + 1e-9f); sv.w = (v.w > 0.f) ? a : ((v.w < 0.f) ? -a : 0.f);
  }
  *(float4*)&out[((size_t)b << 14) + idx] = sv;

  float ss = sv.x * sv.x + sv.y * sv.y + sv.z * sv.z + sv.w * sv.w;
#pragma unroll
  for (int o = 32; o > 0; o >>= 1) ss += __shfl_down(ss, o, 64);
  __shared__ float red[4];
  if ((t & 63) == 0) red[t >> 6] = ss;
  __syncthreads();
  if (t == 0) g_ssq[b * 16 + seg] = red[0] + red[1] + red[2] + red[3];
}

// ---------------------------------------------------------------------------
// Kernel 2b: scale by rsqrt(max(sumsq, 1e-12))
// ---------------------------------------------------------------------------
__global__ void bcnn_scale_kernel(float* __restrict__ out) {
  const int b   = blockIdx.y;
  const int seg = blockIdx.x;
  const int t   = threadIdx.x;

  float tot = 0.f;
#pragma unroll
  for (int i = 0; i < 16; ++i) tot += g_ssq[b * 16 + i];
  const float scale = rsqrtf(fmaxf(tot, 1e-12f));

  const size_t base = ((size_t)b << 14) + seg * 1024 + t * 4;
  float4 v = *(float4*)&out[base];
  v.x *= scale; v.y *= scale; v.z *= scale; v.w *= scale;
  *(float4*)&out[base] = v;
}

extern "C" void kernel_launch(void* const* d_in, const int* in_sizes, int n_in,
                              void* d_out, int out_size, void* d_ws, size_t ws_size,
                              hipStream_t stream) {
  const float* L = (const float*)d_in[0];
  const float* R = (const float*)d_in[1];
  float* out = (float*)d_out;

  dim3 g1(NK, BATCH);
  bcnn_gemm_kernel<<<g1, 512, 0, stream>>>(L, R);

  dim3 g2(16, BATCH);
  bcnn_sqrt_kernel<<<g2, 256, 0, stream>>>(out);
  bcnn_scale_kernel<<<g2, 256, 0, stream>>>(out);
}

// Round 11
// 88.217 us; speedup vs baseline: 1.0374x; 1.0374x over previous
//
#include <hip/hip_runtime.h>
#include <hip/hip_bf16.h>

// Bilinear CNN pooling: dotted[b,c,d] = sum_x L[b,x,c]*R[b,x,d]  (B=32, X=12544, C=128)
// then signed-sqrt + global L2-normalize per batch.
//
// FINAL (= round 6, session best 87.8us): split-bf16 3-pass MFMA GEMM,
// stage-time hi/lo conversion (each element converted once), conflict-free
// XOR LDS layout, raw s_barrier + lgkmcnt(0) only (no vmcnt drain), 3-deep
// register lookahead (the measured optimum: 2-deep +5us, 4-deep +4us),
// NK=8 K-chunks (minimal partial traffic), deterministic partial reduction.
//
// Measured ceiling rationale: 449 MB minimal traffic -> 71us floor + launch/
// epilogue ~8us; this kernel = ~88us (~90% of structural floor). Falsified
// alternatives: conflict-free staging variants (r2/r3), LDS-read cuts (r7),
// barrier-free global-gather (r8), 2x occupancy (r9), 4-deep lookahead (r10).

#define NK      8             // K-chunks per batch
#define KC      1568          // 12544 / 8
#define BK      32            // K per tile
#define NT      49            // KC / BK
#define BATCH   32
#define CDIM    128
#define XDIM    12544

typedef __bf16 bf16x8 __attribute__((ext_vector_type(8)));
typedef float  f32x16 __attribute__((ext_vector_type(16)));

// 16 MB partial buffer + per-segment sumsq; fully rewritten before read each launch.
__device__ float g_part[(size_t)NK * BATCH * CDIM * CDIM];
__device__ float g_ssq[BATCH * 16];

// Split 8 f32 -> RNE-bf16 hi + trunc-bf16 lo, packed into uint4s (validated r1-r10).
__device__ __forceinline__ void split8(const float* f, uint4& hi, uint4& lo) {
  uint xh[8], xl[8];
#pragma unroll
  for (int i = 0; i < 8; ++i) {
    uint u = __float_as_uint(f[i]);
    uint r = u + 0x7FFFu + ((u >> 16) & 1u);        // RNE bf16 in top 16 bits
    xh[i] = r;
    float hif = __uint_as_float(r & 0xFFFF0000u);    // exact hi value
    xl[i] = __float_as_uint(f[i] - hif);             // exact residual, trunc on pack
  }
  hi.x = __builtin_amdgcn_perm(xh[1], xh[0], 0x07060302u);
  hi.y = __builtin_amdgcn_perm(xh[3], xh[2], 0x07060302u);
  hi.z = __builtin_amdgcn_perm(xh[5], xh[4], 0x07060302u);
  hi.w = __builtin_amdgcn_perm(xh[7], xh[6], 0x07060302u);
  lo.x = __builtin_amdgcn_perm(xl[1], xl[0], 0x07060302u);
  lo.y = __builtin_amdgcn_perm(xl[3], xl[2], 0x07060302u);
  lo.z = __builtin_amdgcn_perm(xl[5], xl[4], 0x07060302u);
  lo.w = __builtin_amdgcn_perm(xl[7], xl[6], 0x07060302u);
}

// LDS 16B-unit index for (column c, k-half kh) within one 16-k substep.
// Conflict-free for both the staging b128 writes and the fragment b128 reads.
__device__ __forceinline__ int ldsu(int c, int kh) {
  return ((c << 1) | kh) ^ ((c >> 2) & 7);
}

// ---------------------------------------------------------------------------
// Kernel 1: per (chunk, batch): partial[c][d] = sum_{k in chunk} L[k][c]*R[k][d]
// 512 threads = 8 waves (2x4 grid of 64x32 tiles, 32x32x16 MFMA, 3-pass split).
// LDS: [set][substep][unit]; 64 KB. Tile = 32 k-rows, two 16-k substeps.
// ---------------------------------------------------------------------------
__global__ __launch_bounds__(512, 2)
void bcnn_gemm_kernel(const float* __restrict__ L, const float* __restrict__ R) {
  __shared__ uint4 sAhi[2][2][256], sAlo[2][2][256];
  __shared__ uint4 sBhi[2][2][256], sBlo[2][2][256];

  const int chunk = blockIdx.x;      // 0..7
  const int b     = blockIdx.y;
  const int t     = threadIdx.x;
  const int l     = t & 63;
  const int w     = t >> 6;
  const int wr    = w >> 2;          // 0..1
  const int wc    = w & 3;           // 0..3
  const int lc    = l & 31;
  const int hh    = l >> 5;          // k-half selector within a substep

  // staging: thread owns column sc, k-rows sh*8 .. sh*8+7 of each 32-k tile
  const int sc  = t & 127;
  const int sh  = t >> 7;            // 0..3
  const int sub = sh >> 1;           // substep region 0/1
  const int wu  = ldsu(sc, sh & 1);

  const float* gL = L + ((size_t)b * XDIM + (size_t)chunk * KC + sh * 8) * CDIM + sc;
  const float* gR = R + ((size_t)b * XDIM + (size_t)chunk * KC + sh * 8) * CDIM + sc;

  // fragment units (per substep)
  const int cA0 = wr * 64 + lc;
  const int cA1 = cA0 + 32;
  const int dB  = wc * 32 + lc;
  const int uA0 = ldsu(cA0, hh);
  const int uA1 = ldsu(cA1, hh);
  const int uB  = ldsu(dB,  hh);

  f32x16 acc0 = {};
  f32x16 acc1 = {};

  // three static register-parity sets (tile s has parity s % 3)
  float rlA[8], rrA[8], rlB[8], rrB[8], rlC[8], rrC[8];

#define LOADR(rl, rr, s)                                                        \
  do {                                                                          \
    const float* pL_ = gL + (size_t)(s) * BK * CDIM;                            \
    const float* pR_ = gR + (size_t)(s) * BK * CDIM;                            \
    _Pragma("unroll")                                                           \
    for (int i = 0; i < 8; ++i) { rl[i] = pL_[i * CDIM]; rr[i] = pR_[i * CDIM]; } \
  } while (0)

#define WRITE(rl, rr, set)                                                      \
  do {                                                                          \
    uint4 hi_, lo_;                                                             \
    split8(rl, hi_, lo_);                                                       \
    sAhi[set][sub][wu] = hi_; sAlo[set][sub][wu] = lo_;                         \
    split8(rr, hi_, lo_);                                                       \
    sBhi[set][sub][wu] = hi_; sBlo[set][sub][wu] = lo_;                         \
  } while (0)

#define COMPUTE(set)                                                            \
  do {                                                                          \
    _Pragma("unroll")                                                           \
    for (int ss = 0; ss < 2; ++ss) {                                            \
      bf16x8 ah0 = *(const bf16x8*)&sAhi[set][ss][uA0];                         \
      bf16x8 al0 = *(const bf16x8*)&sAlo[set][ss][uA0];                         \
      bf16x8 ah1 = *(const bf16x8*)&sAhi[set][ss][uA1];                         \
      bf16x8 al1 = *(const bf16x8*)&sAlo[set][ss][uA1];                         \
      bf16x8 bh  = *(const bf16x8*)&sBhi[set][ss][uB];                          \
      bf16x8 bl  = *(const bf16x8*)&sBlo[set][ss][uB];                          \
      acc0 = __builtin_amdgcn_mfma_f32_32x32x16_bf16(ah0, bh, acc0, 0, 0, 0);   \
      acc1 = __builtin_amdgcn_mfma_f32_32x32x16_bf16(ah1, bh, acc1, 0, 0, 0);   \
      acc0 = __builtin_amdgcn_mfma_f32_32x32x16_bf16(ah0, bl, acc0, 0, 0, 0);   \
      acc1 = __builtin_amdgcn_mfma_f32_32x32x16_bf16(ah1, bl, acc1, 0, 0, 0);   \
      acc0 = __builtin_amdgcn_mfma_f32_32x32x16_bf16(al0, bh, acc0, 0, 0, 0);   \
      acc1 = __builtin_amdgcn_mfma_f32_32x32x16_bf16(al1, bh, acc1, 0, 0, 0);   \
    }                                                                           \
  } while (0)

#define BAR()                                                                   \
  do {                                                                          \
    asm volatile("s_waitcnt lgkmcnt(0)" ::: "memory");                          \
    __builtin_amdgcn_s_barrier();                                               \
  } while (0)

  // prologue: tiles 0,1,2 in flight; write tile 0 (waits only its own regs)
  LOADR(rlA, rrA, 0);
  LOADR(rlB, rrB, 1);
  LOADR(rlC, rrC, 2);
  WRITE(rlA, rrA, 0);
  BAR();

  // steady state: iter s -> COMPUTE(tile s, set s&1); issue tile s+3 into
  // parity s%3; WRITE tile s+1 (loaded at iter s-2) into set (s+1)&1.
  // 6-unrolled (lcm(2,3)) for fully static parity/set names.
  for (int it = 0; it < 7; ++it) {
    const int s0 = 6 * it;
    /* s0+0 */ LOADR(rlA, rrA, s0 + 3); COMPUTE(0); WRITE(rlB, rrB, 1); BAR();
    /* s0+1 */ LOADR(rlB, rrB, s0 + 4); COMPUTE(1); WRITE(rlC, rrC, 0); BAR();
    /* s0+2 */ LOADR(rlC, rrC, s0 + 5); COMPUTE(0); WRITE(rlA, rrA, 1); BAR();
    /* s0+3 */ LOADR(rlA, rrA, s0 + 6); COMPUTE(1); WRITE(rlB, rrB, 0); BAR();
    /* s0+4 */ LOADR(rlB, rrB, s0 + 7); COMPUTE(0); WRITE(rlC, rrC, 1); BAR();
    /* s0+5 */ LOADR(rlC, rrC, s0 + 8); COMPUTE(1); WRITE(rlA, rrA, 0); BAR();
  }
  // peeled tail: s = 42..48 (loads stop at tile 48)
  /* s=42 */ LOADR(rlA, rrA, 45); COMPUTE(0); WRITE(rlB, rrB, 1); BAR();
  /* s=43 */ LOADR(rlB, rrB, 46); COMPUTE(1); WRITE(rlC, rrC, 0); BAR();
  /* s=44 */ LOADR(rlC, rrC, 47); COMPUTE(0); WRITE(rlA, rrA, 1); BAR();
  /* s=45 */ LOADR(rlA, rrA, 48); COMPUTE(1); WRITE(rlB, rrB, 0); BAR();
  /* s=46 */ COMPUTE(0); WRITE(rlC, rrC, 1); BAR();
  /* s=47 */ COMPUTE(1); WRITE(rlA, rrA, 0); BAR();
  /* s=48 */ COMPUTE(0);

#undef LOADR
#undef WRITE
#undef COMPUTE
#undef BAR

  // C/D layout (HW-validated): col = lane&31, row = (r&3)+8*(r>>2)+4*hh
  float* outp = g_part + (((size_t)chunk * BATCH + b) << 14);
#pragma unroll
  for (int r = 0; r < 16; ++r) {
    const int row = (r & 3) + ((r >> 2) << 3) + (hh << 2);
    outp[(size_t)(wr * 64 + row) * CDIM + (wc * 32 + lc)]      = acc0[r];
    outp[(size_t)(wr * 64 + 32 + row) * CDIM + (wc * 32 + lc)] = acc1[r];
  }
}

// ---------------------------------------------------------------------------
// Kernel 2a: sum NK partials, signed-sqrt, write sqrted, per-segment sumsq.
// ---------------------------------------------------------------------------
__global__ void bcnn_sqrt_kernel(float* __restrict__ out) {
  const int b   = blockIdx.y;
  const int seg = blockIdx.x;
  const int t   = threadIdx.x;
  const int idx = seg * 1024 + t * 4;

  float4 v = {0.f, 0.f, 0.f, 0.f};
#pragma unroll
  for (int ch = 0; ch < NK; ++ch) {
    const float4 p = *(const float4*)&g_part[(((size_t)ch * BATCH + b) << 14) + idx];
    v.x += p.x; v.y += p.y; v.z += p.z; v.w += p.w;
  }
  float4 sv;
  {
    float a;
    a = sqrtf(fabsf(v.x) + 1e-9f); sv.x = (v.x > 0.f) ? a : ((v.x < 0.f) ? -a : 0.f);
    a = sqrtf(fabsf(v.y) + 1e-9f); sv.y = (v.y > 0.f) ? a : ((v.y < 0.f) ? -a : 0.f);
    a = sqrtf(fabsf(v.z) + 1e-9f); sv.z = (v.z > 0.f) ? a : ((v.z < 0.f) ? -a : 0.f);
    a = sqrtf(fabsf(v.w) + 1e-9f); sv.w = (v.w > 0.f) ? a : ((v.w < 0.f) ? -a : 0.f);
  }
  *(float4*)&out[((size_t)b << 14) + idx] = sv;

  float ss = sv.x * sv.x + sv.y * sv.y + sv.z * sv.z + sv.w * sv.w;
#pragma unroll
  for (int o = 32; o > 0; o >>= 1) ss += __shfl_down(ss, o, 64);
  __shared__ float red[4];
  if ((t & 63) == 0) red[t >> 6] = ss;
  __syncthreads();
  if (t == 0) g_ssq[b * 16 + seg] = red[0] + red[1] + red[2] + red[3];
}

// ---------------------------------------------------------------------------
// Kernel 2b: scale by rsqrt(max(sumsq, 1e-12))
// ---------------------------------------------------------------------------
__global__ void bcnn_scale_kernel(float* __restrict__ out) {
  const int b   = blockIdx.y;
  const int seg = blockIdx.x;
  const int t   = threadIdx.x;

  float tot = 0.f;
#pragma unroll
  for (int i = 0; i < 16; ++i) tot += g_ssq[b * 16 + i];
  const float scale = rsqrtf(fmaxf(tot, 1e-12f));

  const size_t base = ((size_t)b << 14) + seg * 1024 + t * 4;
  float4 v = *(float4*)&out[base];
  v.x *= scale; v.y *= scale; v.z *= scale; v.w *= scale;
  *(float4*)&out[base] = v;
}

extern "C" void kernel_launch(void* const* d_in, const int* in_sizes, int n_in,
                              void* d_out, int out_size, void* d_ws, size_t ws_size,
                              hipStream_t stream) {
  const float* L = (const float*)d_in[0];
  const float* R = (const float*)d_in[1];
  float* out = (float*)d_out;

  dim3 g1(NK, BATCH);
  bcnn_gemm_kernel<<<g1, 512, 0, stream>>>(L, R);

  dim3 g2(16, BATCH);
  bcnn_sqrt_kernel<<<g2, 256, 0, stream>>>(out);
  bcnn_scale_kernel<<<g2, 256, 0, stream>>>(out);
}